// Round 8
// baseline (279.482 us; speedup 1.0000x reference)
//
#include <hip/hip_runtime.h>

typedef _Float16 f16;
typedef _Float16 f16x8 __attribute__((ext_vector_type(8)));
typedef _Float16 f16x4 __attribute__((ext_vector_type(4)));
typedef float f32x4 __attribute__((ext_vector_type(4)));

#define NH 4
#define HD 256
#define BB 4
#define SS 2048
#define HID 1152
#define QKV_N 1536
#define ODIM (NH * HD)

#define QKV16_OFF 0L
#define OBUF_OFF 0L
#define OPART_OFF 16777216L
#define ML_OFF 44040192L
#define QB_OFF 50331648L
#define KB_OFF 67108864L
#define VT_OFF 71303168L
#define WQKVT_OFF 75497472L
#define WOT_OFF 79036416L

// async global->LDS, 16B per lane; LDS dest = wave-uniform base + lane*16
#define GLL16(gp, lp)                                                      \
  __builtin_amdgcn_global_load_lds(                                       \
      (const __attribute__((address_space(1))) char*)(gp),                \
      (__attribute__((address_space(3))) char*)(lp), 16, 0, 0)

// ---------------------------------------------------------------------------
// Transpose + convert to fp16:  dst[c][r] = (f16) src[r][c]
// ---------------------------------------------------------------------------
template <typename ST>
__global__ __launch_bounds__(256) void transpose_cvt(
    const ST* __restrict__ src, long src_ld, long src_bs,
    f16* __restrict__ dst, long dst_ld, long dst_bs) {
  __shared__ float tile[32][33];
  src += (long)blockIdx.z * src_bs;
  dst += (long)blockIdx.z * dst_bs;
  int r0 = blockIdx.y * 32, c0 = blockIdx.x * 32;
  int tc = threadIdx.x & 31, tr = threadIdx.x >> 5;
#pragma unroll
  for (int i = 0; i < 4; ++i)
    tile[tr + i * 8][tc] = (float)src[(long)(r0 + tr + i * 8) * src_ld + c0 + tc];
  __syncthreads();
#pragma unroll
  for (int i = 0; i < 4; ++i)
    dst[(long)(c0 + tr + i * 8) * dst_ld + r0 + tc] = (f16)tile[tc][tr + i * 8];
}

// ---------------------------------------------------------------------------
// GEMM: C[M][N] = A[M][K] (fp16 via global_load_lds, or fp32 reg-staged with
// in-flight cvt) x Bt[N][K] fp16 (global_load_lds). 128x128, BK=64.
// ---------------------------------------------------------------------------
template <typename AT, typename CT>
__global__ __launch_bounds__(256, 3) void gemm_x(
    const AT* __restrict__ A, const f16* __restrict__ Bt,
    CT* __restrict__ C, int K, int N) {
  __shared__ f16 As[128][64];
  __shared__ f16 Bs[128][64];
  int tid = threadIdx.x, wave = tid >> 6, lane = tid & 63;
  int l16 = lane & 15, lhi = lane >> 4;
  int wm = (wave >> 1) * 64, wn = (wave & 1) * 64;
  long bm = (long)blockIdx.x * 128, bn = (long)blockIdx.y * 128;
  f32x4 acc[4][4] = {};

  int srow = wave * 32 + (lane >> 3), scol = (lane & 7) * 8;
  const f16* Bg = Bt + (bn + srow) * (long)K + scol;
  const f16* Agh = nullptr;
  const float* Agf = nullptr;
  int ar = tid >> 2, ac = (tid & 3) * 16;
  if constexpr (sizeof(AT) == 2)
    Agh = (const f16*)A + (bm + srow) * (long)K + scol;
  else
    Agf = (const float*)A + (bm + ar) * (long)K + ac;

  for (int k0 = 0; k0 < K; k0 += 64) {
    if constexpr (sizeof(AT) == 2) {
#pragma unroll
      for (int i = 0; i < 4; ++i)
        GLL16(Agh + k0 + (long)i * 8 * K, &As[wave * 32 + i * 8][0]);
    } else {
#pragma unroll
      for (int g = 0; g < 2; ++g) {
        const float* src = Agf + k0 + (long)g * 64 * K;
        float4 v0 = *(const float4*)(src + 0);
        float4 v1 = *(const float4*)(src + 4);
        float4 v2 = *(const float4*)(src + 8);
        float4 v3 = *(const float4*)(src + 12);
        f16x8 h0 = {(f16)v0.x, (f16)v0.y, (f16)v0.z, (f16)v0.w,
                    (f16)v1.x, (f16)v1.y, (f16)v1.z, (f16)v1.w};
        f16x8 h1 = {(f16)v2.x, (f16)v2.y, (f16)v2.z, (f16)v2.w,
                    (f16)v3.x, (f16)v3.y, (f16)v3.z, (f16)v3.w};
        *(f16x8*)&As[ar + 64 * g][ac] = h0;
        *(f16x8*)&As[ar + 64 * g][ac + 8] = h1;
      }
    }
#pragma unroll
    for (int i = 0; i < 4; ++i)
      GLL16(Bg + k0 + (long)i * 8 * K, &Bs[wave * 32 + i * 8][0]);
    __syncthreads();
#pragma unroll
    for (int kb = 0; kb < 2; ++kb) {
      f16x8 af[4], bf[4];
#pragma unroll
      for (int i = 0; i < 4; ++i)
        af[i] = *(const f16x8*)&As[wm + i * 16 + l16][kb * 32 + lhi * 8];
#pragma unroll
      for (int j = 0; j < 4; ++j)
        bf[j] = *(const f16x8*)&Bs[wn + j * 16 + l16][kb * 32 + lhi * 8];
#pragma unroll
      for (int i = 0; i < 4; ++i)
#pragma unroll
        for (int j = 0; j < 4; ++j)
          acc[i][j] =
              __builtin_amdgcn_mfma_f32_16x16x32_f16(bf[j], af[i], acc[i][j], 0, 0, 0);
    }
    __syncthreads();
  }

#pragma unroll
  for (int i = 0; i < 4; ++i) {
    long m = bm + wm + i * 16 + l16;
#pragma unroll
    for (int j = 0; j < 4; ++j) {
      long n = bn + wn + j * 16 + lhi * 4;
      if constexpr (sizeof(CT) == 2) {
        f16x4 h = {(f16)acc[i][j][0], (f16)acc[i][j][1], (f16)acc[i][j][2],
                   (f16)acc[i][j][3]};
        *(f16x4*)&C[m * N + n] = h;
      } else {
        *(f32x4*)&C[m * N + n] = acc[i][j];
      }
    }
  }
}

// ---------------------------------------------------------------------------
// RMSNorm + RoPE + scale, qkv fp16 -> Q/K fp16
// ---------------------------------------------------------------------------
__device__ __forceinline__ void norm_rope_store(
    const f16* __restrict__ x, const float* __restrict__ w,
    const float* __restrict__ fc, const float* __restrict__ fs,
    f16* __restrict__ dst, float scale, int lane) {
  float x0 = (float)x[lane], x1 = (float)x[lane + 64];
  float x2 = (float)x[lane + 128], x3 = (float)x[lane + 192];
  float ss = x0 * x0 + x1 * x1 + x2 * x2 + x3 * x3;
#pragma unroll
  for (int m = 1; m < 64; m <<= 1) ss += __shfl_xor(ss, m, 64);
  float inv = rsqrtf(ss * (1.0f / 256.0f) + 1e-6f);
  x0 *= inv * (1.0f + w[lane]);
  x1 *= inv * (1.0f + w[lane + 64]);
  x2 *= inv * (1.0f + w[lane + 128]);
  x3 *= inv * (1.0f + w[lane + 192]);
  float c0 = fc[lane], s0 = fs[lane], c1 = fc[lane + 64], s1 = fs[lane + 64];
  dst[lane]       = (f16)((x0 * c0 - x2 * s0) * scale);
  dst[lane + 64]  = (f16)((x1 * c1 - x3 * s1) * scale);
  dst[lane + 128] = (f16)((x0 * s0 + x2 * c0) * scale);
  dst[lane + 192] = (f16)((x1 * s1 + x3 * c1) * scale);
}

__global__ __launch_bounds__(256) void qkv_post(
    const f16* __restrict__ qkv, const float* __restrict__ qnw,
    const float* __restrict__ knw, const float* __restrict__ fcos,
    const float* __restrict__ fsin, f16* __restrict__ Q, f16* __restrict__ Kb) {
  long row = blockIdx.x;
  int b = (int)(row >> 11), s = (int)(row & 2047);
  int wave = threadIdx.x >> 6, lane = threadIdx.x & 63;
  const f16* base = qkv + row * QKV_N;
  const float* fc = fcos + (long)s * 128;
  const float* fs = fsin + (long)s * 128;
  norm_rope_store(base + wave * HD, qnw, fc, fs,
                  Q + ((long)(b * NH + wave) * SS + s) * HD, 0.0625f, lane);
  if (wave == 0)
    norm_rope_store(base + NH * HD, knw, fc, fs, Kb + row * HD, 1.0f, lane);
}

// ---------------------------------------------------------------------------
// Flash attention, causal, GQA. R5 structure (reg-staged LDS tiles, KVBLK=32,
// 4 waves x 16 q-rows) + XOR-swizzled K/V LDS layouts (reads/writes <=2-way):
//   K[32][256]: byte = r*512 + (c ^ ((r&7)<<4))
//   V[256][32]: byte = r*64  + (c ^ ((r&3)<<4))
// Uniform work items (<=22 tiles each): qb<=10 full; qb 11-21 2-way kv-split;
// qb 22-31 3-way kv-split. grid (63, NH, B), ~4 blocks/CU.
// ---------------------------------------------------------------------------
__global__ __launch_bounds__(256, 4) void attn_fwd(
    const f16* __restrict__ Q, const f16* __restrict__ Kb,
    const f16* __restrict__ Vt, f16* __restrict__ O,
    f16* __restrict__ Opart, float2* __restrict__ ml) {
  __shared__ f16 Klds[32 * 256];
  __shared__ f16 Vlds[256 * 32];
  __shared__ f16 Plds[4][16][40];
  int it = blockIdx.x, h = blockIdx.y, b = blockIdx.z;
  int qb, t0, t1, slot = 0;
  bool split;
  if (it < 11) {
    qb = it; t0 = 0; t1 = 2 * qb + 2; split = false;
  } else {
    int j = it - 11, c, nch, lbase;
    if (j < 22) {
      qb = 11 + (j >> 1); c = j & 1; nch = 2; lbase = (qb - 11) * 2;
    } else {
      int jj = j - 22, q3 = jj / 3;
      qb = 22 + q3; c = jj - q3 * 3; nch = 3; lbase = 22 + q3 * 3;
    }
    int tiles = 2 * qb + 2;
    t0 = tiles * c / nch;
    t1 = tiles * (c + 1) / nch;
    split = true;
    slot = (b * NH + h) * 52 + lbase + c;
  }
  int tid = threadIdx.x, wave = tid >> 6, lane = tid & 63;
  int l16 = lane & 15, lhi = lane >> 4;
  int q0 = qb * 64 + wave * 16;

  const f16* Kg = Kb + (long)b * SS * HD;
  const f16* Vg = Vt + (long)b * HD * SS;

  // Q fragments (B-operand: q on lane&15, d-slice on lhi)
  f16x8 qf[8];
  const f16* Qbase = Q + ((long)(b * NH + h) * SS + q0 + l16) * HD + lhi * 8;
#pragma unroll
  for (int kb = 0; kb < 8; ++kb) qf[kb] = *(const f16x8*)(Qbase + kb * 32);

  f32x4 o[16] = {};
  float m_i = -1e30f, l_i = 0.f;

  // staging params (global reads linear/coalesced; LDS writes swizzled)
  int kr = tid >> 5, kc16 = (tid & 31) * 16;  // K rows kr+8i, col byte kc16
  int rv = tid >> 2, vc16 = (tid & 3) * 16;   // V rows rv+64i, col byte vc16
  char* kls = (char*)Klds;
  char* vls = (char*)Vlds;
  int kwsw = kc16 ^ (kr << 4);              // K write: ^(row&7)<<4, row&7==kr
  int vwsw = vc16 ^ ((rv & 3) << 4);        // V write: ^(row&3)<<4
  // read bases
  const char* krd = kls + l16 * 512;        // + cf*8192 + ((kb*64+lhi*16)^kswz)
  int kswz = (l16 & 7) << 4;
  const char* vrd = vls + l16 * 64 + ((lhi * 16) ^ ((l16 & 3) << 4));  // + nf*1024

  for (int t = t0; t < t1; ++t) {
    long kv0 = (long)t * 32;
    __syncthreads();  // prior tile's LDS reads complete
#pragma unroll
    for (int i = 0; i < 4; ++i) {
      uint4 kval = *(const uint4*)((const char*)(Kg + (kv0 + kr + 8 * i) * HD) + kc16);
      *(uint4*)(kls + (kr + 8 * i) * 512 + kwsw) = kval;
    }
#pragma unroll
    for (int i = 0; i < 4; ++i) {
      uint4 vval = *(const uint4*)((const char*)(Vg + (long)(rv + 64 * i) * SS + kv0) + vc16);
      *(uint4*)(vls + (rv + 64 * i) * 64 + vwsw) = vval;
    }
    __syncthreads();  // staged tile visible

    // QK^T swapped: mfma(K, Q) -> D[kv_local][q=l16]
    f32x4 sc[2] = {};
    __builtin_amdgcn_s_setprio(1);
#pragma unroll
    for (int kb = 0; kb < 8; ++kb) {
#pragma unroll
      for (int cf = 0; cf < 2; ++cf) {
        f16x8 kf = *(const f16x8*)(krd + cf * 8192 + ((kb * 64 + lhi * 16) ^ kswz));
        sc[cf] = __builtin_amdgcn_mfma_f32_16x16x32_f16(kf, qf[kb], sc[cf], 0, 0, 0);
      }
    }
    __builtin_amdgcn_s_setprio(0);

    // online softmax: lane owns q-row q0+l16, 8 scores in-register
    float p[8];
    float mx = -1e30f;
    int qrow = q0 + l16;
    if (t >= 2 * qb) {  // diagonal tiles need the causal mask
#pragma unroll
      for (int cf = 0; cf < 2; ++cf)
#pragma unroll
        for (int r = 0; r < 4; ++r) {
          int kv = (int)kv0 + cf * 16 + lhi * 4 + r;
          float s = (kv <= qrow) ? sc[cf][r] : -1e30f;
          p[cf * 4 + r] = s;
          mx = fmaxf(mx, s);
        }
    } else {
#pragma unroll
      for (int i = 0; i < 8; ++i) {
        float s = sc[i >> 2][i & 3];
        p[i] = s;
        mx = fmaxf(mx, s);
      }
    }
    mx = fmaxf(mx, __shfl_xor(mx, 16));
    mx = fmaxf(mx, __shfl_xor(mx, 32));
    float mn = fmaxf(m_i, mx);
    float scl = __expf(m_i - mn);
    float rs = 0.f;
#pragma unroll
    for (int i = 0; i < 8; ++i) {
      p[i] = __expf(p[i] - mn);
      rs += p[i];
    }
    rs += __shfl_xor(rs, 16);
    rs += __shfl_xor(rs, 32);
    l_i = l_i * scl + rs;
    m_i = mn;

    // P -> f16 into per-wave LDS [q][kv]
#pragma unroll
    for (int cf = 0; cf < 2; ++cf) {
      f16x4 hp = {(f16)p[cf * 4], (f16)p[cf * 4 + 1], (f16)p[cf * 4 + 2],
                  (f16)p[cf * 4 + 3]};
      *(f16x4*)&Plds[wave][l16][cf * 16 + lhi * 4] = hp;
    }

    // rescale O by scl of the owning q-row
    float s0 = __shfl(scl, lhi * 4 + 0);
    float s1 = __shfl(scl, lhi * 4 + 1);
    float s2 = __shfl(scl, lhi * 4 + 2);
    float s3 = __shfl(scl, lhi * 4 + 3);
#pragma unroll
    for (int nf = 0; nf < 16; ++nf) {
      o[nf][0] *= s0;
      o[nf][1] *= s1;
      o[nf][2] *= s2;
      o[nf][3] *= s3;
    }

    // PV: o[q=lhi*4+r][d=nf*16+l16] += P x V
    f16x8 pa = *(const f16x8*)&Plds[wave][l16][lhi * 8];
    __builtin_amdgcn_s_setprio(1);
#pragma unroll
    for (int nf = 0; nf < 16; ++nf) {
      f16x8 vf = *(const f16x8*)(vrd + nf * 1024);
      o[nf] = __builtin_amdgcn_mfma_f32_16x16x32_f16(pa, vf, o[nf], 0, 0, 0);
    }
    __builtin_amdgcn_s_setprio(0);
  }

  // epilogue
  float inv = 1.0f / l_i;
  float i0 = __shfl(inv, lhi * 4 + 0);
  float i1 = __shfl(inv, lhi * 4 + 1);
  float i2 = __shfl(inv, lhi * 4 + 2);
  float i3 = __shfl(inv, lhi * 4 + 3);
  float ir[4] = {i0, i1, i2, i3};
  if (!split) {
#pragma unroll
    for (int r = 0; r < 4; ++r) {
      long srow = q0 + lhi * 4 + r;
      f16* Orow = O + ((long)b * SS + srow) * ODIM + h * HD + l16;
#pragma unroll
      for (int nf = 0; nf < 16; ++nf) Orow[nf * 16] = (f16)(o[nf][r] * ir[r]);
    }
  } else {
#pragma unroll
    for (int r = 0; r < 4; ++r) {
      int rloc = wave * 16 + lhi * 4 + r;
      f16* Prow = Opart + ((long)slot * 64 + rloc) * HD + l16;
#pragma unroll
      for (int nf = 0; nf < 16; ++nf) Prow[nf * 16] = (f16)(o[nf][r] * ir[r]);
    }
    if (lane < 16) {
      float2 v; v.x = m_i; v.y = l_i;
      ml[(long)slot * 64 + wave * 16 + lane] = v;
    }
  }
}

// ---------------------------------------------------------------------------
// Combine 2- or 3-way kv-split partials for qb in [11, 31].
// grid (21, NH, B), 256 thr: thread = (row 0..63, quarter-of-d)
// ---------------------------------------------------------------------------
__global__ __launch_bounds__(256) void attn_combine(
    const f16* __restrict__ Opart, const float2* __restrict__ ml,
    f16* __restrict__ O) {
  int x = blockIdx.x, h = blockIdx.y, b = blockIdx.z;
  int qb = 11 + x;
  int nch = (qb < 22) ? 2 : 3;
  int lbase = (qb < 22) ? (qb - 11) * 2 : 22 + (qb - 22) * 3;
  long slot0 = (long)(b * NH + h) * 52 + lbase;
  int tid = threadIdx.x;
  int r = tid >> 2, d0 = (tid & 3) * 64;
  float m[3], l[3], w[3];
  float M = -1e30f;
#pragma unroll
  for (int c = 0; c < 3; ++c)
    if (c < nch) {
      float2 v = ml[(slot0 + c) * 64 + r];
      m[c] = v.x; l[c] = v.y;
      M = fmaxf(M, v.x);
    }
  float sum = 0.f;
#pragma unroll
  for (int c = 0; c < 3; ++c)
    if (c < nch) { w[c] = l[c] * __expf(m[c] - M); sum += w[c]; }
  float inv = 1.0f / sum;
#pragma unroll
  for (int c = 0; c < 3; ++c)
    if (c < nch) w[c] *= inv;
  f16* Orow = O + ((long)b * SS + qb * 64 + r) * ODIM + h * HD + d0;
#pragma unroll
  for (int i = 0; i < 8; ++i) {
    float acc[8] = {};
#pragma unroll
    for (int c = 0; c < 3; ++c)
      if (c < nch) {
        f16x8 xv = *(const f16x8*)(Opart + ((slot0 + c) * 64 + r) * HD + d0 + i * 8);
#pragma unroll
        for (int j = 0; j < 8; ++j) acc[j] += w[c] * (float)xv[j];
      }
    f16x8 z;
#pragma unroll
    for (int j = 0; j < 8; ++j) z[j] = (f16)acc[j];
    *(f16x8*)(Orow + i * 8) = z;
  }
}

// ---------------------------------------------------------------------------
extern "C" void kernel_launch(void* const* d_in, const int* in_sizes, int n_in,
                              void* d_out, int out_size, void* d_ws, size_t ws_size,
                              hipStream_t stream) {
  const float* hidden = (const float*)d_in[0];
  const float* fcos = (const float*)d_in[2];
  const float* fsin = (const float*)d_in[3];
  const float* wqkv = (const float*)d_in[4];
  const float* qnw = (const float*)d_in[5];
  const float* knw = (const float*)d_in[6];
  const float* wo = (const float*)d_in[7];
  float* out = (float*)d_out;

  char* ws = (char*)d_ws;
  f16* qkv16 = (f16*)(ws + QKV16_OFF);   // 25.2 MB, dead before attn
  f16* Obuf = (f16*)(ws + OBUF_OFF);     // 16.8 MB
  f16* Opart = (f16*)(ws + OPART_OFF);   // 27.3 MB (832 slots x 64 x 256 f16)
  float2* ml = (float2*)(ws + ML_OFF);   // 0.43 MB
  f16* Qb = (f16*)(ws + QB_OFF);
  f16* Kb = (f16*)(ws + KB_OFF);
  f16* Vt = (f16*)(ws + VT_OFF);
  f16* wqkvt = (f16*)(ws + WQKVT_OFF);
  f16* wot = (f16*)(ws + WOT_OFF);

  // weight transposes -> fp16 [N][K]
  transpose_cvt<float><<<dim3(QKV_N / 32, HID / 32, 1), 256, 0, stream>>>(
      wqkv, QKV_N, 0, wqkvt, HID, 0);
  transpose_cvt<float><<<dim3(HID / 32, ODIM / 32, 1), 256, 0, stream>>>(
      wo, HID, 0, wot, ODIM, 0);

  // QKV GEMM (A fp32 with fused cvt) -> qkv fp16
  gemm_x<float, f16><<<dim3(BB * SS / 128, QKV_N / 128), 256, 0, stream>>>(
      hidden, wqkvt, qkv16, HID, QKV_N);

  // RMSNorm + RoPE -> Q, K fp16
  qkv_post<<<dim3(BB * SS), 256, 0, stream>>>(qkv16, qnw, knw, fcos, fsin, Qb, Kb);

  // V slice transpose: qkv16[b][s][1280+d] -> Vt[b][d][s]
  transpose_cvt<f16><<<dim3(HD / 32, SS / 32, BB), 256, 0, stream>>>(
      qkv16 + 1280, QKV_N, (long)SS * QKV_N, Vt, SS, (long)HD * SS);

  // flash attention -> Obuf fp16
  attn_fwd<<<dim3(63, NH, BB), 256, 0, stream>>>(Qb, Kb, Vt, Obuf, Opart, ml);
  attn_combine<<<dim3(21, NH, BB), 256, 0, stream>>>(Opart, ml, Obuf);

  // output GEMM -> d_out fp32
  gemm_x<f16, float><<<dim3(BB * SS / 128, HID / 128), 256, 0, stream>>>(
      Obuf, wot, out, ODIM, HID);
}

// Round 9
// 240.635 us; speedup vs baseline: 1.1614x; 1.1614x over previous
//
#include <hip/hip_runtime.h>

typedef _Float16 f16;
typedef _Float16 f16x8 __attribute__((ext_vector_type(8)));
typedef _Float16 f16x4 __attribute__((ext_vector_type(4)));
typedef float f32x4 __attribute__((ext_vector_type(4)));

#define NH 4
#define HD 256
#define BB 4
#define SS 2048
#define HID 1152
#define QKV_N 1536
#define ODIM (NH * HD)

#define QKV16_OFF 0L
#define HID16_OFF 25165824L
#define OBUF_OFF 0L
#define OPART_OFF 16777216L
#define ML_OFF 44040192L
#define QB_OFF 50331648L
#define KB_OFF 67108864L
#define VT_OFF 71303168L
#define WQKVT_OFF 75497472L
#define WOT_OFF 79036416L

// async global->LDS, 16B per lane; LDS dest = wave-uniform base + lane*16
#define GLL16(gp, lp)                                                      \
  __builtin_amdgcn_global_load_lds(                                       \
      (const __attribute__((address_space(1))) char*)(gp),                \
      (__attribute__((address_space(3))) char*)(lp), 16, 0, 0)

// ---------------------------------------------------------------------------
// fp32 -> fp16 bulk convert (vectorized, grid-stride)
// ---------------------------------------------------------------------------
__global__ __launch_bounds__(256) void cvt_f32_to_f16(
    const float* __restrict__ s, f16* __restrict__ d, long n) {
  long i = ((long)blockIdx.x * 256 + threadIdx.x) * 8;
  long stride = (long)gridDim.x * 256 * 8;
  for (; i < n; i += stride) {
    float4 a = *(const float4*)(s + i);
    float4 b = *(const float4*)(s + i + 4);
    f16x8 h = {(f16)a.x, (f16)a.y, (f16)a.z, (f16)a.w,
               (f16)b.x, (f16)b.y, (f16)b.z, (f16)b.w};
    *(f16x8*)(d + i) = h;
  }
}

// ---------------------------------------------------------------------------
// Transpose + convert to fp16:  dst[c][r] = (f16) src[r][c]
// ---------------------------------------------------------------------------
template <typename ST>
__global__ __launch_bounds__(256) void transpose_cvt(
    const ST* __restrict__ src, long src_ld, long src_bs,
    f16* __restrict__ dst, long dst_ld, long dst_bs) {
  __shared__ float tile[32][33];
  src += (long)blockIdx.z * src_bs;
  dst += (long)blockIdx.z * dst_bs;
  int r0 = blockIdx.y * 32, c0 = blockIdx.x * 32;
  int tc = threadIdx.x & 31, tr = threadIdx.x >> 5;
#pragma unroll
  for (int i = 0; i < 4; ++i)
    tile[tr + i * 8][tc] = (float)src[(long)(r0 + tr + i * 8) * src_ld + c0 + tc];
  __syncthreads();
#pragma unroll
  for (int i = 0; i < 4; ++i)
    dst[(long)(c0 + tr + i * 8) * dst_ld + r0 + tc] = (f16)tile[tc][tr + i * 8];
}

// ---------------------------------------------------------------------------
// GEMM: C[M][N] = A[M][K] fp16 x Bt[N][K] fp16, C fp16 or fp32.
// m97 structure: 128x128 tile, BK=64, linear LDS, global_load_lds 16B.
// ---------------------------------------------------------------------------
template <typename CT>
__global__ __launch_bounds__(256, 3) void gemm_f16(
    const f16* __restrict__ A, const f16* __restrict__ Bt,
    CT* __restrict__ C, int K, int N) {
  __shared__ f16 As[128][64];
  __shared__ f16 Bs[128][64];
  int tid = threadIdx.x, wave = tid >> 6, lane = tid & 63;
  int l16 = lane & 15, lhi = lane >> 4;
  int wm = (wave >> 1) * 64, wn = (wave & 1) * 64;
  long bm = (long)blockIdx.x * 128, bn = (long)blockIdx.y * 128;
  f32x4 acc[4][4] = {};

  int srow = wave * 32 + (lane >> 3);
  int scol = (lane & 7) * 8;
  const f16* Ag = A + (bm + srow) * (long)K + scol;
  const f16* Bg = Bt + (bn + srow) * (long)K + scol;

  for (int k0 = 0; k0 < K; k0 += 64) {
#pragma unroll
    for (int i = 0; i < 4; ++i)
      GLL16(Ag + k0 + (long)i * 8 * K, &As[wave * 32 + i * 8][0]);
#pragma unroll
    for (int i = 0; i < 4; ++i)
      GLL16(Bg + k0 + (long)i * 8 * K, &Bs[wave * 32 + i * 8][0]);
    __syncthreads();
#pragma unroll
    for (int kb = 0; kb < 2; ++kb) {
      f16x8 af[4], bf[4];
#pragma unroll
      for (int i = 0; i < 4; ++i)
        af[i] = *(const f16x8*)&As[wm + i * 16 + l16][kb * 32 + lhi * 8];
#pragma unroll
      for (int j = 0; j < 4; ++j)
        bf[j] = *(const f16x8*)&Bs[wn + j * 16 + l16][kb * 32 + lhi * 8];
#pragma unroll
      for (int i = 0; i < 4; ++i)
#pragma unroll
        for (int j = 0; j < 4; ++j)
          acc[i][j] =
              __builtin_amdgcn_mfma_f32_16x16x32_f16(bf[j], af[i], acc[i][j], 0, 0, 0);
    }
    __syncthreads();
  }

#pragma unroll
  for (int i = 0; i < 4; ++i) {
    long m = bm + wm + i * 16 + l16;
#pragma unroll
    for (int j = 0; j < 4; ++j) {
      long n = bn + wn + j * 16 + lhi * 4;
      if constexpr (sizeof(CT) == 2) {
        f16x4 h = {(f16)acc[i][j][0], (f16)acc[i][j][1], (f16)acc[i][j][2],
                   (f16)acc[i][j][3]};
        *(f16x4*)&C[m * N + n] = h;
      } else {
        *(f32x4*)&C[m * N + n] = acc[i][j];
      }
    }
  }
}

// ---------------------------------------------------------------------------
// RMSNorm + RoPE + scale, qkv fp16 -> Q/K fp16
// ---------------------------------------------------------------------------
__device__ __forceinline__ void norm_rope_store(
    const f16* __restrict__ x, const float* __restrict__ w,
    const float* __restrict__ fc, const float* __restrict__ fs,
    f16* __restrict__ dst, float scale, int lane) {
  float x0 = (float)x[lane], x1 = (float)x[lane + 64];
  float x2 = (float)x[lane + 128], x3 = (float)x[lane + 192];
  float ss = x0 * x0 + x1 * x1 + x2 * x2 + x3 * x3;
#pragma unroll
  for (int m = 1; m < 64; m <<= 1) ss += __shfl_xor(ss, m, 64);
  float inv = rsqrtf(ss * (1.0f / 256.0f) + 1e-6f);
  x0 *= inv * (1.0f + w[lane]);
  x1 *= inv * (1.0f + w[lane + 64]);
  x2 *= inv * (1.0f + w[lane + 128]);
  x3 *= inv * (1.0f + w[lane + 192]);
  float c0 = fc[lane], s0 = fs[lane], c1 = fc[lane + 64], s1 = fs[lane + 64];
  dst[lane]       = (f16)((x0 * c0 - x2 * s0) * scale);
  dst[lane + 64]  = (f16)((x1 * c1 - x3 * s1) * scale);
  dst[lane + 128] = (f16)((x0 * s0 + x2 * c0) * scale);
  dst[lane + 192] = (f16)((x1 * s1 + x3 * c1) * scale);
}

__global__ __launch_bounds__(256) void qkv_post(
    const f16* __restrict__ qkv, const float* __restrict__ qnw,
    const float* __restrict__ knw, const float* __restrict__ fcos,
    const float* __restrict__ fsin, f16* __restrict__ Q, f16* __restrict__ Kb) {
  long row = blockIdx.x;
  int b = (int)(row >> 11), s = (int)(row & 2047);
  int wave = threadIdx.x >> 6, lane = threadIdx.x & 63;
  const f16* base = qkv + row * QKV_N;
  const float* fc = fcos + (long)s * 128;
  const float* fs = fsin + (long)s * 128;
  norm_rope_store(base + wave * HD, qnw, fc, fs,
                  Q + ((long)(b * NH + wave) * SS + s) * HD, 0.0625f, lane);
  if (wave == 0)
    norm_rope_store(base + NH * HD, knw, fc, fs, Kb + row * HD, 1.0f, lane);
}

// ---------------------------------------------------------------------------
// Flash attention, causal, GQA. R8 body (reg-staged swizzled LDS, KVBLK=32,
// 63-item uniform kv-split) + XCD-pinned 1D grid: bid&7 -> xcd = 2*b+parity,
// so each XCD touches ONE batch's K/V (2MB < 4MB L2) -> no L2 thrash.
// grid: 1024 blocks (16 idle), 4 blocks/CU.
// ---------------------------------------------------------------------------
__global__ __launch_bounds__(256, 4) void attn_fwd(
    const f16* __restrict__ Q, const f16* __restrict__ Kb,
    const f16* __restrict__ Vt, f16* __restrict__ O,
    f16* __restrict__ Opart, float2* __restrict__ ml) {
  __shared__ f16 Klds[32 * 256];
  __shared__ f16 Vlds[256 * 32];
  __shared__ f16 Plds[4][16][40];
  // --- XCD-pinned decode ---
  int bid = blockIdx.x;
  int xcd = bid & 7, slotid = bid >> 3;
  int b = xcd >> 1, par = xcd & 1;
  int h = slotid >> 5, ithalf = slotid & 31;
  int it = ithalf * 2 + par;
  if (it >= 63) return;

  int qb, t0, t1, slot = 0;
  bool split;
  if (it < 11) {
    qb = it; t0 = 0; t1 = 2 * qb + 2; split = false;
  } else {
    int j = it - 11, c, nch, lbase;
    if (j < 22) {
      qb = 11 + (j >> 1); c = j & 1; nch = 2; lbase = (qb - 11) * 2;
    } else {
      int jj = j - 22, q3 = jj / 3;
      qb = 22 + q3; c = jj - q3 * 3; nch = 3; lbase = 22 + q3 * 3;
    }
    int tiles = 2 * qb + 2;
    t0 = tiles * c / nch;
    t1 = tiles * (c + 1) / nch;
    split = true;
    slot = (b * NH + h) * 52 + lbase + c;
  }
  int tid = threadIdx.x, wave = tid >> 6, lane = tid & 63;
  int l16 = lane & 15, lhi = lane >> 4;
  int q0 = qb * 64 + wave * 16;

  const f16* Kg = Kb + (long)b * SS * HD;
  const f16* Vg = Vt + (long)b * HD * SS;

  // Q fragments (B-operand: q on lane&15, d-slice on lhi)
  f16x8 qf[8];
  const f16* Qbase = Q + ((long)(b * NH + h) * SS + q0 + l16) * HD + lhi * 8;
#pragma unroll
  for (int kb = 0; kb < 8; ++kb) qf[kb] = *(const f16x8*)(Qbase + kb * 32);

  f32x4 o[16] = {};
  float m_i = -1e30f, l_i = 0.f;

  // staging params (global reads linear/coalesced; LDS writes swizzled)
  int kr = tid >> 5, kc16 = (tid & 31) * 16;  // K rows kr+8i, col byte kc16
  int rv = tid >> 2, vc16 = (tid & 3) * 16;   // V rows rv+64i, col byte vc16
  char* kls = (char*)Klds;
  char* vls = (char*)Vlds;
  int kwsw = kc16 ^ (kr << 4);              // K write: ^(row&7)<<4, row&7==kr
  int vwsw = vc16 ^ ((rv & 3) << 4);        // V write: ^(row&3)<<4
  // read bases
  const char* krd = kls + l16 * 512;        // + cf*8192 + ((kb*64+lhi*16)^kswz)
  int kswz = (l16 & 7) << 4;
  const char* vrd = vls + l16 * 64 + ((lhi * 16) ^ ((l16 & 3) << 4));  // + nf*1024

  for (int t = t0; t < t1; ++t) {
    long kv0 = (long)t * 32;
    __syncthreads();  // prior tile's LDS reads complete
#pragma unroll
    for (int i = 0; i < 4; ++i) {
      uint4 kval = *(const uint4*)((const char*)(Kg + (kv0 + kr + 8 * i) * HD) + kc16);
      *(uint4*)(kls + (kr + 8 * i) * 512 + kwsw) = kval;
    }
#pragma unroll
    for (int i = 0; i < 4; ++i) {
      uint4 vval = *(const uint4*)((const char*)(Vg + (long)(rv + 64 * i) * SS + kv0) + vc16);
      *(uint4*)(vls + (rv + 64 * i) * 64 + vwsw) = vval;
    }
    __syncthreads();  // staged tile visible

    // QK^T swapped: mfma(K, Q) -> D[kv_local][q=l16]
    f32x4 sc[2] = {};
    __builtin_amdgcn_s_setprio(1);
#pragma unroll
    for (int kb = 0; kb < 8; ++kb) {
#pragma unroll
      for (int cf = 0; cf < 2; ++cf) {
        f16x8 kf = *(const f16x8*)(krd + cf * 8192 + ((kb * 64 + lhi * 16) ^ kswz));
        sc[cf] = __builtin_amdgcn_mfma_f32_16x16x32_f16(kf, qf[kb], sc[cf], 0, 0, 0);
      }
    }
    __builtin_amdgcn_s_setprio(0);

    // online softmax: lane owns q-row q0+l16, 8 scores in-register
    float p[8];
    float mx = -1e30f;
    int qrow = q0 + l16;
    if (t >= 2 * qb) {  // diagonal tiles need the causal mask
#pragma unroll
      for (int cf = 0; cf < 2; ++cf)
#pragma unroll
        for (int r = 0; r < 4; ++r) {
          int kv = (int)kv0 + cf * 16 + lhi * 4 + r;
          float s = (kv <= qrow) ? sc[cf][r] : -1e30f;
          p[cf * 4 + r] = s;
          mx = fmaxf(mx, s);
        }
    } else {
#pragma unroll
      for (int i = 0; i < 8; ++i) {
        float s = sc[i >> 2][i & 3];
        p[i] = s;
        mx = fmaxf(mx, s);
      }
    }
    mx = fmaxf(mx, __shfl_xor(mx, 16));
    mx = fmaxf(mx, __shfl_xor(mx, 32));
    float mn = fmaxf(m_i, mx);
    float scl = __expf(m_i - mn);
    float rs = 0.f;
#pragma unroll
    for (int i = 0; i < 8; ++i) {
      p[i] = __expf(p[i] - mn);
      rs += p[i];
    }
    rs += __shfl_xor(rs, 16);
    rs += __shfl_xor(rs, 32);
    l_i = l_i * scl + rs;
    m_i = mn;

    // P -> f16 into per-wave LDS [q][kv]
#pragma unroll
    for (int cf = 0; cf < 2; ++cf) {
      f16x4 hp = {(f16)p[cf * 4], (f16)p[cf * 4 + 1], (f16)p[cf * 4 + 2],
                  (f16)p[cf * 4 + 3]};
      *(f16x4*)&Plds[wave][l16][cf * 16 + lhi * 4] = hp;
    }

    // rescale O by scl of the owning q-row
    float s0 = __shfl(scl, lhi * 4 + 0);
    float s1 = __shfl(scl, lhi * 4 + 1);
    float s2 = __shfl(scl, lhi * 4 + 2);
    float s3 = __shfl(scl, lhi * 4 + 3);
#pragma unroll
    for (int nf = 0; nf < 16; ++nf) {
      o[nf][0] *= s0;
      o[nf][1] *= s1;
      o[nf][2] *= s2;
      o[nf][3] *= s3;
    }

    // PV: o[q=lhi*4+r][d=nf*16+l16] += P x V
    f16x8 pa = *(const f16x8*)&Plds[wave][l16][lhi * 8];
    __builtin_amdgcn_s_setprio(1);
#pragma unroll
    for (int nf = 0; nf < 16; ++nf) {
      f16x8 vf = *(const f16x8*)(vrd + nf * 1024);
      o[nf] = __builtin_amdgcn_mfma_f32_16x16x32_f16(pa, vf, o[nf], 0, 0, 0);
    }
    __builtin_amdgcn_s_setprio(0);
  }

  // epilogue
  float inv = 1.0f / l_i;
  float i0 = __shfl(inv, lhi * 4 + 0);
  float i1 = __shfl(inv, lhi * 4 + 1);
  float i2 = __shfl(inv, lhi * 4 + 2);
  float i3 = __shfl(inv, lhi * 4 + 3);
  float ir[4] = {i0, i1, i2, i3};
  if (!split) {
#pragma unroll
    for (int r = 0; r < 4; ++r) {
      long srow = q0 + lhi * 4 + r;
      f16* Orow = O + ((long)b * SS + srow) * ODIM + h * HD + l16;
#pragma unroll
      for (int nf = 0; nf < 16; ++nf) Orow[nf * 16] = (f16)(o[nf][r] * ir[r]);
    }
  } else {
#pragma unroll
    for (int r = 0; r < 4; ++r) {
      int rloc = wave * 16 + lhi * 4 + r;
      f16* Prow = Opart + ((long)slot * 64 + rloc) * HD + l16;
#pragma unroll
      for (int nf = 0; nf < 16; ++nf) Prow[nf * 16] = (f16)(o[nf][r] * ir[r]);
    }
    if (lane < 16) {
      float2 v; v.x = m_i; v.y = l_i;
      ml[(long)slot * 64 + wave * 16 + lane] = v;
    }
  }
}

// ---------------------------------------------------------------------------
// Combine 2- or 3-way kv-split partials for qb in [11, 31].
// grid (21, NH, B), 256 thr: thread = (row 0..63, quarter-of-d)
// ---------------------------------------------------------------------------
__global__ __launch_bounds__(256) void attn_combine(
    const f16* __restrict__ Opart, const float2* __restrict__ ml,
    f16* __restrict__ O) {
  int x = blockIdx.x, h = blockIdx.y, b = blockIdx.z;
  int qb = 11 + x;
  int nch = (qb < 22) ? 2 : 3;
  int lbase = (qb < 22) ? (qb - 11) * 2 : 22 + (qb - 22) * 3;
  long slot0 = (long)(b * NH + h) * 52 + lbase;
  int tid = threadIdx.x;
  int r = tid >> 2, d0 = (tid & 3) * 64;
  float m[3], l[3], w[3];
  float M = -1e30f;
#pragma unroll
  for (int c = 0; c < 3; ++c)
    if (c < nch) {
      float2 v = ml[(slot0 + c) * 64 + r];
      m[c] = v.x; l[c] = v.y;
      M = fmaxf(M, v.x);
    }
  float sum = 0.f;
#pragma unroll
  for (int c = 0; c < 3; ++c)
    if (c < nch) { w[c] = l[c] * __expf(m[c] - M); sum += w[c]; }
  float inv = 1.0f / sum;
#pragma unroll
  for (int c = 0; c < 3; ++c)
    if (c < nch) w[c] *= inv;
  f16* Orow = O + ((long)b * SS + qb * 64 + r) * ODIM + h * HD + d0;
#pragma unroll
  for (int i = 0; i < 8; ++i) {
    float acc[8] = {};
#pragma unroll
    for (int c = 0; c < 3; ++c)
      if (c < nch) {
        f16x8 xv = *(const f16x8*)(Opart + ((slot0 + c) * 64 + r) * HD + d0 + i * 8);
#pragma unroll
        for (int j = 0; j < 8; ++j) acc[j] += w[c] * (float)xv[j];
      }
    f16x8 z;
#pragma unroll
    for (int j = 0; j < 8; ++j) z[j] = (f16)acc[j];
    *(f16x8*)(Orow + i * 8) = z;
  }
}

// ---------------------------------------------------------------------------
extern "C" void kernel_launch(void* const* d_in, const int* in_sizes, int n_in,
                              void* d_out, int out_size, void* d_ws, size_t ws_size,
                              hipStream_t stream) {
  const float* hidden = (const float*)d_in[0];
  const float* fcos = (const float*)d_in[2];
  const float* fsin = (const float*)d_in[3];
  const float* wqkv = (const float*)d_in[4];
  const float* qnw = (const float*)d_in[5];
  const float* knw = (const float*)d_in[6];
  const float* wo = (const float*)d_in[7];
  float* out = (float*)d_out;

  char* ws = (char*)d_ws;
  f16* qkv16 = (f16*)(ws + QKV16_OFF);   // 0..25.2M (dead after V-transpose)
  f16* hid16 = (f16*)(ws + HID16_OFF);   // 25.2..44.0M (dead after gemm1)
  f16* Obuf = (f16*)(ws + OBUF_OFF);     // 0..16.8M
  f16* Opart = (f16*)(ws + OPART_OFF);   // 16.8..44.0M (over dead qkv16/hid16)
  float2* ml = (float2*)(ws + ML_OFF);   // 44.04M
  f16* Qb = (f16*)(ws + QB_OFF);
  f16* Kb = (f16*)(ws + KB_OFF);
  f16* Vt = (f16*)(ws + VT_OFF);
  f16* wqkvt = (f16*)(ws + WQKVT_OFF);
  f16* wot = (f16*)(ws + WOT_OFF);

  // hidden fp32 -> fp16
  cvt_f32_to_f16<<<2048, 256, 0, stream>>>(hidden, hid16, (long)BB * SS * HID);

  // weight transposes -> fp16 [N][K]
  transpose_cvt<float><<<dim3(QKV_N / 32, HID / 32, 1), 256, 0, stream>>>(
      wqkv, QKV_N, 0, wqkvt, HID, 0);
  transpose_cvt<float><<<dim3(HID / 32, ODIM / 32, 1), 256, 0, stream>>>(
      wo, HID, 0, wot, ODIM, 0);

  // QKV GEMM -> qkv fp16
  gemm_f16<f16><<<dim3(BB * SS / 128, QKV_N / 128), 256, 0, stream>>>(
      hid16, wqkvt, qkv16, HID, QKV_N);

  // RMSNorm + RoPE -> Q, K fp16
  qkv_post<<<dim3(BB * SS), 256, 0, stream>>>(qkv16, qnw, knw, fcos, fsin, Qb, Kb);

  // V slice transpose: qkv16[b][s][1280+d] -> Vt[b][d][s]
  transpose_cvt<f16><<<dim3(HD / 32, SS / 32, BB), 256, 0, stream>>>(
      qkv16 + 1280, QKV_N, (long)SS * QKV_N, Vt, SS, (long)HD * SS);

  // flash attention -> Obuf fp16 (XCD-pinned 1D grid)
  attn_fwd<<<dim3(1024), 256, 0, stream>>>(Qb, Kb, Vt, Obuf, Opart, ml);
  attn_combine<<<dim3(21, NH, BB), 256, 0, stream>>>(Opart, ml, Obuf);

  // output GEMM -> d_out fp32
  gemm_f16<float><<<dim3(BB * SS / 128, HID / 128), 256, 0, stream>>>(
      Obuf, wot, out, ODIM, HID);
}